// Round 1
// baseline (5858.525 us; speedup 1.0000x reference)
//
#include <hip/hip_runtime.h>

typedef __attribute__((ext_vector_type(8))) short s8b;     // 8 x bf16 (4 VGPRs)
typedef __attribute__((ext_vector_type(16))) float v16f;   // 32x32 MFMA acc
typedef __attribute__((ext_vector_type(4)))  float v4f;    // 16x16 MFMA acc
typedef __attribute__((ext_vector_type(4)))  unsigned int u32x4;
typedef unsigned short u16;

__device__ __forceinline__ float clamp01(float v) {
  return __builtin_fminf(__builtin_fmaxf(v, 0.0f), 1.0f);
}

// split fp32 -> bf16 hi (truncate) + bf16 lo (truncated remainder); hi+lo ~ 2^-16 rel
__device__ __forceinline__ void split1(float f, u16 &h, u16 &l) {
  unsigned u = __builtin_bit_cast(unsigned, f);
  unsigned hu = u & 0xffff0000u;
  float lf = f - __builtin_bit_cast(float, hu);
  h = (u16)(u >> 16);
  l = (u16)(__builtin_bit_cast(unsigned, lf) >> 16);
}

__device__ __forceinline__ v16f mfma32(s8b a, s8b b, v16f c) {
  return __builtin_amdgcn_mfma_f32_32x32x16_bf16(a, b, c, 0, 0, 0);
}
__device__ __forceinline__ v4f mfma16(s8b a, s8b b, v4f c) {
  return __builtin_amdgcn_mfma_f32_16x16x32_bf16(a, b, c, 0, 0, 0);
}

// ---------------- prep: split weights into hi/lo bf16 arrays -----------------
__global__ void k_prep_w(const float* __restrict__ W2, const float* __restrict__ W3,
                         const float* __restrict__ W4,
                         u16* __restrict__ w2h, u16* __restrict__ w2l,
                         u16* __restrict__ w3h, u16* __restrict__ w3l,
                         u16* __restrict__ w4h, u16* __restrict__ w4l) {
  int i = blockIdx.x * 256 + threadIdx.x;   // grid covers 200704 exactly
  if (i < 65536) {
    u16 h, lo;
    split1(W2[i], h, lo); w2h[i] = h; w2l[i] = lo;
    split1(W3[i], h, lo); w3h[i] = h; w3l[i] = lo;
  }
  if (i < 200704) {
    u16 h, lo;
    split1(W4[i], h, lo); w4h[i] = h; w4l[i] = lo;
  }
}

__global__ void k_prep_small(const float* __restrict__ W0, const float* __restrict__ b0,
                             const float* __restrict__ W1,
                             u16* __restrict__ w1h, u16* __restrict__ w1l,
                             u16* __restrict__ w0h, u16* __restrict__ w0l,
                             float* __restrict__ b0p) {
  int i = blockIdx.x * 256 + threadIdx.x;
  if (i < 4096) {                    // W1 padded [256][16], k<10 valid
    int n = i >> 4, k = i & 15;
    float v = (k < 10) ? W1[n * 10 + k] : 0.0f;
    u16 h, lo; split1(v, h, lo); w1h[i] = h; w1l[i] = lo;
  } else if (i < 8192) {             // W0 padded [16][256], n<10 valid
    int j = i - 4096; int n = j >> 8, k = j & 255;
    float v = (n < 10) ? W0[n * 256 + k] : 0.0f;
    u16 h, lo; split1(v, h, lo); w0h[j] = h; w0l[j] = lo;
  } else if (i < 8208) {             // b0 padded [16]
    int k = i - 8192;
    b0p[k] = (k < 10) ? b0[k] : 0.0f;
  }
}

// ---------------- drive = data @ W4^T + b4  (once) ---------------------------
__device__ __forceinline__ void split_pack8(v4f x0, v4f x1, s8b &hi, s8b &lo) {
  float f[8];
  #pragma unroll
  for (int j = 0; j < 4; ++j) { f[j] = x0[j]; f[4 + j] = x1[j]; }
  u32x4 vh, vl;
  #pragma unroll
  for (int j = 0; j < 4; ++j) {
    unsigned u0 = __builtin_bit_cast(unsigned, f[2 * j]);
    unsigned u1 = __builtin_bit_cast(unsigned, f[2 * j + 1]);
    unsigned h0 = u0 & 0xffff0000u, h1 = u1 & 0xffff0000u;
    float l0 = f[2 * j]     - __builtin_bit_cast(float, h0);
    float l1 = f[2 * j + 1] - __builtin_bit_cast(float, h1);
    vh[j] = (u0 >> 16) | h1;
    vl[j] = (__builtin_bit_cast(unsigned, l0) >> 16) |
            (__builtin_bit_cast(unsigned, l1) & 0xffff0000u);
  }
  hi = __builtin_bit_cast(s8b, vh);
  lo = __builtin_bit_cast(s8b, vl);
}

__global__ void __launch_bounds__(256, 1) k_drive(
    const float* __restrict__ data, const u16* __restrict__ w4h,
    const u16* __restrict__ w4l, const float* __restrict__ b4,
    float* __restrict__ drive) {
  const int tid = threadIdx.x;
  const int w = tid >> 6, l = tid & 63;
  const int m = l & 31, g = l >> 5;
  const int rb = blockIdx.x * 64;
  const int nbase = w * 64;
  float b4v0 = b4[nbase + m], b4v1 = b4[nbase + 32 + m];
  v16f acc[2][2];
  #pragma unroll
  for (int r = 0; r < 16; ++r) {
    acc[0][0][r] = b4v0; acc[0][1][r] = b4v1;
    acc[1][0][r] = b4v0; acc[1][1][r] = b4v1;
  }
  for (int kt = 0; kt < 49; ++kt) {            // 784 = 49*16 exact
    int k0 = kt * 16 + g * 8;
    s8b aH[2], aL[2], bH[2], bL[2];
    #pragma unroll
    for (int mt = 0; mt < 2; ++mt) {
      const float* p = data + (size_t)(rb + 32 * mt + m) * 784 + k0;
      v4f x0 = *(const v4f*)p;
      v4f x1 = *(const v4f*)(p + 4);
      split_pack8(x0, x1, aH[mt], aL[mt]);
    }
    #pragma unroll
    for (int nt = 0; nt < 2; ++nt) {
      int off = (nbase + 32 * nt + m) * 784 + k0;
      bH[nt] = *(const s8b*)(w4h + off);
      bL[nt] = *(const s8b*)(w4l + off);
    }
    #pragma unroll
    for (int mt = 0; mt < 2; ++mt)
      #pragma unroll
      for (int nt = 0; nt < 2; ++nt) {
        acc[mt][nt] = mfma32(aH[mt], bH[nt], acc[mt][nt]);
        acc[mt][nt] = mfma32(aL[mt], bH[nt], acc[mt][nt]);
        acc[mt][nt] = mfma32(aH[mt], bL[nt], acc[mt][nt]);
      }
  }
  #pragma unroll
  for (int mt = 0; mt < 2; ++mt)
    #pragma unroll
    for (int nt = 0; nt < 2; ++nt)
      #pragma unroll
      for (int r = 0; r < 16; ++r) {
        int row = rb + 32 * mt + (r & 3) + 8 * (r >> 2) + 4 * g;
        int col = nbase + 32 * nt + m;
        drive[(size_t)row * 256 + col] = acc[mt][nt][r];
      }
}

// ---------------- main persistent stepper ------------------------------------
struct FragKT { s8b aH[2], aL[2], bH[2], bL[2]; };

__device__ __forceinline__ FragKT load_kt256(const u16* sH, const u16* sL,
    const u16* wH, const u16* wL, int kt, int m, int g, int nbase) {
  FragKT f;
  const int q = 2 * kt + g;
  const int sh = ((q ^ (m & 7)) << 3);          // XOR swizzle, 8-elem units
  #pragma unroll
  for (int mt = 0; mt < 2; ++mt) {
    int idx = (32 * mt + m) * 256 + sh;
    f.aH[mt] = *(const s8b*)(sH + idx);
    f.aL[mt] = *(const s8b*)(sL + idx);
  }
  const int koff = kt * 16 + g * 8;
  #pragma unroll
  for (int nt = 0; nt < 2; ++nt) {
    int off = (nbase + 32 * nt + m) * 256 + koff;
    f.bH[nt] = *(const s8b*)(wH + off);
    f.bL[nt] = *(const s8b*)(wL + off);
  }
  return f;
}

__device__ __forceinline__ void mfma_kt(const FragKT& f, v16f acc[2][2]) {
  #pragma unroll
  for (int mt = 0; mt < 2; ++mt)
    #pragma unroll
    for (int nt = 0; nt < 2; ++nt) {
      acc[mt][nt] = mfma32(f.aH[mt], f.bH[nt], acc[mt][nt]);
      acc[mt][nt] = mfma32(f.aL[mt], f.bH[nt], acc[mt][nt]);
      acc[mt][nt] = mfma32(f.aH[mt], f.bL[nt], acc[mt][nt]);
    }
}

__device__ __forceinline__ void gemm256(const u16* sH, const u16* sL,
    const u16* wH, const u16* wL, int m, int g, int nbase, v16f acc[2][2]) {
  FragKT cur = load_kt256(sH, sL, wH, wL, 0, m, g, nbase);
  #pragma unroll
  for (int kt = 0; kt < 16; ++kt) {
    FragKT nxt;
    if (kt < 15) nxt = load_kt256(sH, sL, wH, wL, kt + 1, m, g, nbase);
    mfma_kt(cur, acc);
    if (kt < 15) cur = nxt;
  }
}

struct FragC { s8b aH[4], aL[4], bH, bL; };

__device__ __forceinline__ FragC load_ktC(const u16* s1H, const u16* s1L,
    const u16* w0h, const u16* w0l, int kt, int m16, int g4) {
  FragC f;
  const int q = kt * 4 + g4;
  #pragma unroll
  for (int mt = 0; mt < 4; ++mt) {
    int row = 16 * mt + m16;
    int idx = row * 256 + ((q ^ (row & 7)) << 3);
    f.aH[mt] = *(const s8b*)(s1H + idx);
    f.aL[mt] = *(const s8b*)(s1L + idx);
  }
  int off = m16 * 256 + kt * 32 + g4 * 8;
  f.bH = *(const s8b*)(w0h + off);
  f.bL = *(const s8b*)(w0l + off);
  return f;
}

__global__ void __launch_bounds__(256, 1) k_main(
    const float* __restrict__ s0g, const float* __restrict__ s1g,
    const float* __restrict__ s2g, const float* __restrict__ b2,
    const int* __restrict__ Tp,
    const u16* __restrict__ w2h, const u16* __restrict__ w2l,
    const u16* __restrict__ w3h, const u16* __restrict__ w3l,
    const u16* __restrict__ w1h, const u16* __restrict__ w1l,
    const u16* __restrict__ w0h, const u16* __restrict__ w0l,
    const float* __restrict__ b0p, const float* __restrict__ drive,
    float* __restrict__ out0, float* __restrict__ out1, float* __restrict__ out2) {
  extern __shared__ u16 smem[];
  u16* s1H = smem;            // [64][256] bf16-hi, swizzled
  u16* s1L = smem + 16384;
  u16* s2H = smem + 32768;
  u16* s2L = smem + 49152;
  u16* s0H = smem + 65536;    // [64][16]
  u16* s0L = smem + 66560;    // total 67584 u16 = 135168 B

  const int tid = threadIdx.x;
  const int w = tid >> 6, l = tid & 63;
  const int m = l & 31, g = l >> 5;
  const int m16 = l & 15, g4 = l >> 4;
  const int rb = blockIdx.x * 64;
  const int nbase = w * 64;

  // init states into LDS (split hi/lo, swizzled)
  for (int i = tid; i < 16384; i += 256) {
    int row = i >> 8, col = i & 255;
    int idx = row * 256 + ((((col >> 3) ^ (row & 7)) << 3)) + (col & 7);
    u16 h, lo;
    split1(s1g[(size_t)(rb + row) * 256 + col], h, lo); s1H[idx] = h; s1L[idx] = lo;
    split1(s2g[(size_t)(rb + row) * 256 + col], h, lo); s2H[idx] = h; s2L[idx] = lo;
  }
  for (int i = tid; i < 1024; i += 256) {
    int row = i >> 4, col = i & 15;
    float v = (col < 10) ? s0g[(rb + row) * 10 + col] : 0.0f;
    u16 h, lo; split1(v, h, lo);
    s0H[i] = h; s0L[i] = lo;
  }

  float b2v0 = b2[nbase + m], b2v1 = b2[nbase + 32 + m];
  float b0v = b0p[m16];
  v16f dr[2][2];
  #pragma unroll
  for (int mt = 0; mt < 2; ++mt)
    #pragma unroll
    for (int nt = 0; nt < 2; ++nt)
      #pragma unroll
      for (int r = 0; r < 16; ++r) {
        int row = rb + 32 * mt + (r & 3) + 8 * (r >> 2) + 4 * g;
        int col = nbase + 32 * nt + m;
        dr[mt][nt][r] = drive[(size_t)row * 256 + col];
      }
  const int T = Tp[0];
  __syncthreads();

  for (int t = 0; t < T; ++t) {
    const bool last = (t == T - 1);

    // n2 = clamp(drive + s1 @ W3^T)
    v16f acc2[2][2];
    acc2[0][0] = dr[0][0]; acc2[0][1] = dr[0][1];
    acc2[1][0] = dr[1][0]; acc2[1][1] = dr[1][1];
    gemm256(s1H, s1L, w3h, w3l, m, g, nbase, acc2);

    // n1 = clamp(b2 + s0 @ W1^T + s2 @ W2^T)
    v16f acc1[2][2];
    #pragma unroll
    for (int r = 0; r < 16; ++r) {
      acc1[0][0][r] = b2v0; acc1[0][1][r] = b2v1;
      acc1[1][0][r] = b2v0; acc1[1][1][r] = b2v1;
    }
    {
      s8b a0H[2], a0L[2], bH[2], bL[2];
      #pragma unroll
      for (int mt = 0; mt < 2; ++mt) {
        int idx = (32 * mt + m) * 16 + g * 8;
        a0H[mt] = *(const s8b*)(s0H + idx);
        a0L[mt] = *(const s8b*)(s0L + idx);
      }
      #pragma unroll
      for (int nt = 0; nt < 2; ++nt) {
        int off = (nbase + 32 * nt + m) * 16 + g * 8;
        bH[nt] = *(const s8b*)(w1h + off);
        bL[nt] = *(const s8b*)(w1l + off);
      }
      #pragma unroll
      for (int mt = 0; mt < 2; ++mt)
        #pragma unroll
        for (int nt = 0; nt < 2; ++nt) {
          acc1[mt][nt] = mfma32(a0H[mt], bH[nt], acc1[mt][nt]);
          acc1[mt][nt] = mfma32(a0L[mt], bH[nt], acc1[mt][nt]);
          acc1[mt][nt] = mfma32(a0H[mt], bL[nt], acc1[mt][nt]);
        }
    }
    gemm256(s2H, s2L, w2h, w2l, m, g, nbase, acc1);

    // n0 = clamp(b0 + s1 @ W0^T)   (16x16x32, all waves redundantly)
    v4f acc0[4];
    #pragma unroll
    for (int mt = 0; mt < 4; ++mt)
      #pragma unroll
      for (int r = 0; r < 4; ++r) acc0[mt][r] = b0v;
    {
      FragC cur = load_ktC(s1H, s1L, w0h, w0l, 0, m16, g4);
      #pragma unroll
      for (int kt = 0; kt < 8; ++kt) {
        FragC nxt;
        if (kt < 7) nxt = load_ktC(s1H, s1L, w0h, w0l, kt + 1, m16, g4);
        #pragma unroll
        for (int mt = 0; mt < 4; ++mt) {
          acc0[mt] = mfma16(cur.aH[mt], cur.bH, acc0[mt]);
          acc0[mt] = mfma16(cur.aL[mt], cur.bH, acc0[mt]);
          acc0[mt] = mfma16(cur.aH[mt], cur.bL, acc0[mt]);
        }
        if (kt < 7) cur = nxt;
      }
    }

    __syncthreads();   // all reads of old states done

    #pragma unroll
    for (int mt = 0; mt < 2; ++mt)
      #pragma unroll
      for (int nt = 0; nt < 2; ++nt)
        #pragma unroll
        for (int r = 0; r < 16; ++r) {
          int row = 32 * mt + (r & 3) + 8 * (r >> 2) + 4 * g;
          int col = nbase + 32 * nt + m;
          int idx = row * 256 + ((((col >> 3) ^ (row & 7)) << 3)) + (col & 7);
          float v1 = clamp01(acc1[mt][nt][r]);
          float v2 = clamp01(acc2[mt][nt][r]);
          u16 h, lo;
          split1(v1, h, lo); s1H[idx] = h; s1L[idx] = lo;
          split1(v2, h, lo); s2H[idx] = h; s2L[idx] = lo;
          if (last) {
            out1[(size_t)(rb + row) * 256 + col] = v1;
            out2[(size_t)(rb + row) * 256 + col] = v2;
          }
        }
    if (w == 0) {
      #pragma unroll
      for (int mt = 0; mt < 4; ++mt)
        #pragma unroll
        for (int r = 0; r < 4; ++r) {
          int row = 16 * mt + g4 * 4 + r;
          int col = m16;
          float v0 = clamp01(acc0[mt][r]);
          if (col < 10) {
            u16 h, lo; split1(v0, h, lo);
            s0H[row * 16 + col] = h; s0L[row * 16 + col] = lo;
            if (last) out0[(rb + row) * 10 + col] = v0;
          }
        }
    }
    __syncthreads();   // writes visible before next step
  }
}

// ---------------- launcher ---------------------------------------------------
extern "C" void kernel_launch(void* const* d_in, const int* in_sizes, int n_in,
                              void* d_out, int out_size, void* d_ws, size_t ws_size,
                              hipStream_t stream) {
  const float* data = (const float*)d_in[0];
  const float* s0g  = (const float*)d_in[1];
  const float* s1g  = (const float*)d_in[2];
  const float* s2g  = (const float*)d_in[3];
  const float* W0   = (const float*)d_in[4];
  const float* b0   = (const float*)d_in[5];
  const float* W1   = (const float*)d_in[6];
  const float* W2   = (const float*)d_in[7];
  const float* b2   = (const float*)d_in[8];
  const float* W3   = (const float*)d_in[9];
  const float* W4   = (const float*)d_in[10];
  const float* b4   = (const float*)d_in[11];
  const int*   Tp   = (const int*)d_in[12];

  char* ws = (char*)d_ws;
  float* drive = (float*)ws;                       // 16,777,216 B
  u16* w2h = (u16*)(ws + 16777216);
  u16* w2l = w2h + 65536;
  u16* w3h = w2l + 65536;
  u16* w3l = w3h + 65536;
  u16* w4h = w3l + 65536;
  u16* w4l = w4h + 200704;
  u16* w1h = w4l + 200704;
  u16* w1l = w1h + 4096;
  u16* w0h = w1l + 4096;
  u16* w0l = w0h + 4096;
  float* b0p = (float*)(w0l + 4096);               // total ~18.2 MB of ws

  float* out0 = (float*)d_out;
  float* out1 = out0 + 16384 * 10;
  float* out2 = out1 + 16384 * 256;

  hipFuncSetAttribute((const void*)k_main,
                      hipFuncAttributeMaxDynamicSharedMemorySize, 135168);

  k_prep_w<<<784, 256, 0, stream>>>(W2, W3, W4, w2h, w2l, w3h, w3l, w4h, w4l);
  k_prep_small<<<33, 256, 0, stream>>>(W0, b0, W1, w1h, w1l, w0h, w0l, b0p);
  k_drive<<<256, 256, 0, stream>>>(data, w4h, w4l, b4, drive);
  k_main<<<256, 256, 135168, stream>>>(s0g, s1g, s2g, b2, Tp,
      w2h, w2l, w3h, w3l, w1h, w1l, w0h, w0l, b0p, drive, out0, out1, out2);
}

// Round 2
// 1772.540 us; speedup vs baseline: 3.3052x; 3.3052x over previous
//
#include <hip/hip_runtime.h>

typedef __attribute__((ext_vector_type(8))) short s8b;       // 8 x bf16
typedef __attribute__((ext_vector_type(16))) float v16f;     // 32x32 f32 acc
typedef __attribute__((ext_vector_type(4)))  float v4f;
typedef __attribute__((ext_vector_type(4)))  unsigned int u32x4;
typedef __attribute__((ext_vector_type(4)))  int i32x4;      // 16 x i8 operand
typedef __attribute__((ext_vector_type(16))) int i32x16;     // 32x32 i32 acc
typedef unsigned short u16;
typedef unsigned int u32;

__device__ __forceinline__ float clamp01(float v) {
  return __builtin_fminf(__builtin_fmaxf(v, 0.0f), 1.0f);
}

// fp32 -> bf16 hi/lo split (for W1/W4 paths)
__device__ __forceinline__ void split1(float f, u16 &h, u16 &l) {
  unsigned u = __builtin_bit_cast(unsigned, f);
  unsigned hu = u & 0xffff0000u;
  float lf = f - __builtin_bit_cast(float, hu);
  h = (u16)(u >> 16);
  l = (u16)(__builtin_bit_cast(unsigned, lf) >> 16);
}

__device__ __forceinline__ v16f mfma32(s8b a, s8b b, v16f c) {
  return __builtin_amdgcn_mfma_f32_32x32x16_bf16(a, b, c, 0, 0, 0);
}
__device__ __forceinline__ i32x16 mfma_i8_32(i32x4 a, i32x4 b, i32x16 c) {
  return __builtin_amdgcn_mfma_i32_32x32x32_i8(a, b, c, 0, 0, 0);
}
__device__ __forceinline__ i32x4 mfma_i8_16(i32x4 a, i32x4 b, i32x4 c) {
  return __builtin_amdgcn_mfma_i32_16x16x64_i8(a, b, c, 0, 0, 0);
}

// state quantization: Q14 fixed point, v assumed in [0,1] (init states are 0)
__device__ __forceinline__ u16 enc_q(float v) {
  int q = (int)rintf(v * 16384.0f);
  int h = (q + 128) >> 8;             // 0..64
  int lo = q - (h << 8);              // -128..127
  return (u16)((h & 0xff) | ((lo & 0xff) << 8));
}
__device__ __forceinline__ float dec_q(u16 e) {
  int h = e & 0xff;
  int lo = (int)(signed char)(e >> 8);
  return (float)((h << 8) + lo) * (1.0f / 16384.0f);
}

// unpack 16 packed u16 (h|l<<8) -> i8x16 h-frag and l-frag via v_perm
__device__ __forceinline__ void unpack_hl(u32x4 A, u32x4 B, i32x4 &h, i32x4 &l) {
  const unsigned SH = 0x06040200u, SL = 0x07050301u;
  h.x = (int)__builtin_amdgcn_perm(A.y, A.x, SH);
  h.y = (int)__builtin_amdgcn_perm(A.w, A.z, SH);
  h.z = (int)__builtin_amdgcn_perm(B.y, B.x, SH);
  h.w = (int)__builtin_amdgcn_perm(B.w, B.z, SH);
  l.x = (int)__builtin_amdgcn_perm(A.y, A.x, SL);
  l.y = (int)__builtin_amdgcn_perm(A.w, A.z, SL);
  l.z = (int)__builtin_amdgcn_perm(B.y, B.x, SL);
  l.w = (int)__builtin_amdgcn_perm(B.w, B.z, SL);
}

// ---------------- prep kernels ----------------------------------------------
// W2/W3 -> i8 Q18 h/l; W0 (padded [16][256]) -> i8 Q18; W4 -> bf16 h/l
__global__ void k_prep_w(const float* __restrict__ W2, const float* __restrict__ W3,
                         const float* __restrict__ W4, const float* __restrict__ W0,
                         signed char* __restrict__ w2h, signed char* __restrict__ w2l,
                         signed char* __restrict__ w3h, signed char* __restrict__ w3l,
                         signed char* __restrict__ w0h, signed char* __restrict__ w0l,
                         u16* __restrict__ w4h, u16* __restrict__ w4l) {
  int i = blockIdx.x * 256 + threadIdx.x;   // grid covers 200704
  if (i < 65536) {
    int q = (int)rintf(W2[i] * 262144.0f);
    int h = (q + 128) >> 8; w2h[i] = (signed char)h; w2l[i] = (signed char)(q - (h << 8));
    q = (int)rintf(W3[i] * 262144.0f);
    h = (q + 128) >> 8; w3h[i] = (signed char)h; w3l[i] = (signed char)(q - (h << 8));
  }
  if (i < 4096) {                           // W0 padded [16][256]
    int n = i >> 8, k = i & 255;
    float v = (n < 10) ? W0[n * 256 + k] : 0.0f;
    int q = (int)rintf(v * 262144.0f);
    int h = (q + 128) >> 8; w0h[i] = (signed char)h; w0l[i] = (signed char)(q - (h << 8));
  }
  if (i < 200704) {
    u16 h, lo;
    split1(W4[i], h, lo); w4h[i] = h; w4l[i] = lo;
  }
}

__global__ void k_prep_small(const float* __restrict__ W1, const float* __restrict__ b0,
                             u16* __restrict__ w1h, u16* __restrict__ w1l,
                             float* __restrict__ b0p) {
  int i = blockIdx.x * 256 + threadIdx.x;
  if (i < 4096) {                    // W1 padded [256][16]
    int n = i >> 4, k = i & 15;
    float v = (k < 10) ? W1[n * 10 + k] : 0.0f;
    u16 h, lo; split1(v, h, lo); w1h[i] = h; w1l[i] = lo;
  } else if (i < 4112) {
    int k = i - 4096;
    b0p[k] = (k < 10) ? b0[k] : 0.0f;
  }
}

// ---------------- drive = data @ W4^T + b4  (bf16 3-pass, once) --------------
__device__ __forceinline__ void split_pack8(v4f x0, v4f x1, s8b &hi, s8b &lo) {
  float f[8];
  #pragma unroll
  for (int j = 0; j < 4; ++j) { f[j] = x0[j]; f[4 + j] = x1[j]; }
  u32x4 vh, vl;
  #pragma unroll
  for (int j = 0; j < 4; ++j) {
    unsigned u0 = __builtin_bit_cast(unsigned, f[2 * j]);
    unsigned u1 = __builtin_bit_cast(unsigned, f[2 * j + 1]);
    unsigned h0 = u0 & 0xffff0000u, h1 = u1 & 0xffff0000u;
    float l0 = f[2 * j]     - __builtin_bit_cast(float, h0);
    float l1 = f[2 * j + 1] - __builtin_bit_cast(float, h1);
    vh[j] = (u0 >> 16) | h1;
    vl[j] = (__builtin_bit_cast(unsigned, l0) >> 16) |
            (__builtin_bit_cast(unsigned, l1) & 0xffff0000u);
  }
  hi = __builtin_bit_cast(s8b, vh);
  lo = __builtin_bit_cast(s8b, vl);
}

__global__ void __launch_bounds__(256, 1) k_drive(
    const float* __restrict__ data, const u16* __restrict__ w4h,
    const u16* __restrict__ w4l, const float* __restrict__ b4,
    float* __restrict__ drive) {
  const int tid = threadIdx.x;
  const int w = tid >> 6, l = tid & 63;
  const int m = l & 31, g = l >> 5;
  const int rb = blockIdx.x * 64;
  const int nbase = w * 64;
  float b4v0 = b4[nbase + m], b4v1 = b4[nbase + 32 + m];
  v16f acc[2][2];
  #pragma unroll
  for (int r = 0; r < 16; ++r) {
    acc[0][0][r] = b4v0; acc[0][1][r] = b4v1;
    acc[1][0][r] = b4v0; acc[1][1][r] = b4v1;
  }
  for (int kt = 0; kt < 49; ++kt) {
    int k0 = kt * 16 + g * 8;
    s8b aH[2], aL[2], bH[2], bL[2];
    #pragma unroll
    for (int mt = 0; mt < 2; ++mt) {
      const float* p = data + (size_t)(rb + 32 * mt + m) * 784 + k0;
      v4f x0 = *(const v4f*)p;
      v4f x1 = *(const v4f*)(p + 4);
      split_pack8(x0, x1, aH[mt], aL[mt]);
    }
    #pragma unroll
    for (int nt = 0; nt < 2; ++nt) {
      int off = (nbase + 32 * nt + m) * 784 + k0;
      bH[nt] = *(const s8b*)(w4h + off);
      bL[nt] = *(const s8b*)(w4l + off);
    }
    #pragma unroll
    for (int mt = 0; mt < 2; ++mt)
      #pragma unroll
      for (int nt = 0; nt < 2; ++nt) {
        acc[mt][nt] = mfma32(aH[mt], bH[nt], acc[mt][nt]);
        acc[mt][nt] = mfma32(aL[mt], bH[nt], acc[mt][nt]);
        acc[mt][nt] = mfma32(aH[mt], bL[nt], acc[mt][nt]);
      }
  }
  #pragma unroll
  for (int mt = 0; mt < 2; ++mt)
    #pragma unroll
    for (int nt = 0; nt < 2; ++nt)
      #pragma unroll
      for (int r = 0; r < 16; ++r) {
        int row = rb + 32 * mt + (r & 3) + 8 * (r >> 2) + 4 * g;
        int col = nbase + 32 * nt + m;
        drive[(size_t)row * 256 + col] = acc[mt][nt][r];
      }
}

// ---------------- main persistent stepper (i8) -------------------------------
// K=256 i8 gemm: A = packed state in LDS (swizzled), B = i8 weights [256][256]
__device__ __forceinline__ void gemm_i8(const u16* __restrict__ sP,
    const signed char* __restrict__ wh, const signed char* __restrict__ wl,
    int m, int g, int nbase, i32x16 hh[2], i32x16 cr[2]) {
  const signed char* wp = wh + (nbase + m) * 256 + g * 16;
  const signed char* wq = wl + (nbase + m) * 256 + g * 16;
  const u16* a0p = sP + m * 256;
  const u16* a1p = sP + (m + 32) * 256;
  const int sx = m & 3;
  #pragma unroll
  for (int kt = 0; kt < 8; ++kt) {
    const int sl = 2 * kt + g;
    const int so = ((sl ^ sx) << 4);
    u32x4 A0  = *(const u32x4*)(a0p + so);
    u32x4 A0b = *(const u32x4*)(a0p + so + 8);
    u32x4 A1  = *(const u32x4*)(a1p + so);
    u32x4 A1b = *(const u32x4*)(a1p + so + 8);
    i32x4 bh = *(const i32x4*)(wp + kt * 32);
    i32x4 bl = *(const i32x4*)(wq + kt * 32);
    i32x4 a0h, a0l, a1h, a1l;
    unpack_hl(A0, A0b, a0h, a0l);
    unpack_hl(A1, A1b, a1h, a1l);
    hh[0] = mfma_i8_32(a0h, bh, hh[0]);
    hh[1] = mfma_i8_32(a1h, bh, hh[1]);
    cr[0] = mfma_i8_32(a0l, bh, cr[0]);
    cr[1] = mfma_i8_32(a1l, bh, cr[1]);
    cr[0] = mfma_i8_32(a0h, bl, cr[0]);
    cr[1] = mfma_i8_32(a1h, bl, cr[1]);
  }
}

__global__ void __launch_bounds__(512, 2) k_main(
    const float* __restrict__ s0g, const float* __restrict__ s1g,
    const float* __restrict__ s2g, const float* __restrict__ b2,
    const int* __restrict__ Tp,
    const signed char* __restrict__ w2h, const signed char* __restrict__ w2l,
    const signed char* __restrict__ w3h, const signed char* __restrict__ w3l,
    const signed char* __restrict__ w0h, const signed char* __restrict__ w0l,
    const u16* __restrict__ w1h, const u16* __restrict__ w1l,
    const float* __restrict__ b0p, const float* __restrict__ drive,
    float* __restrict__ out0, float* __restrict__ out1, float* __restrict__ out2) {
  extern __shared__ u16 smem[];
  u16* s1P = smem;               // [64][256] packed h|l, 32B-slot swizzled
  u16* s2P = smem + 16384;
  u16* s0h = smem + 32768;       // [64][16] bf16 hi
  u16* s0l = smem + 33792;       // [64][16] bf16 lo   (total 69632 B)

  const int tid = threadIdx.x;
  const int w = tid >> 6, l = tid & 63;      // 8 waves
  const int m = l & 31, g = l >> 5;
  const int m16 = l & 15, g4 = l >> 4;       // for 16x16 path (waves 0-3)
  const int rb = blockIdx.x * 64;
  const int nbase = w * 32;                  // this wave's 32 output cols

  // ---- init states into LDS ----
  for (int i = tid; i < 16384; i += 512) {
    int row = i >> 8, col = i & 255;
    int idx = row * 256 + ((((col >> 4) ^ (row & 3)) << 4)) + (col & 15);
    s1P[idx] = enc_q(s1g[(size_t)(rb + row) * 256 + col]);
    s2P[idx] = enc_q(s2g[(size_t)(rb + row) * 256 + col]);
  }
  for (int i = tid; i < 1024; i += 512) {
    int row = i >> 4, col = i & 15;
    float v = (col < 10) ? s0g[(rb + row) * 10 + col] : 0.0f;
    u16 h, lo; split1(v, h, lo);
    s0h[i] = h; s0l[i] = lo;
  }

  const float b2v = b2[nbase + m];
  const float b0v = (m16 < 16) ? b0p[m16] : 0.0f;
  float dr[2][16];
  #pragma unroll
  for (int mt = 0; mt < 2; ++mt)
    #pragma unroll
    for (int r = 0; r < 16; ++r) {
      int row = rb + 32 * mt + (r & 3) + 8 * (r >> 2) + 4 * g;
      dr[mt][r] = drive[(size_t)row * 256 + nbase + m];
    }
  const int T = Tp[0];
  const int cslot = (nbase + m) >> 4;        // write-back column slot
  const int cm = m & 15;
  __syncthreads();

  for (int t = 0; t < T; ++t) {
    const bool last = (t == T - 1);

    // ---- n2 = clamp(drive + s1 @ W3^T) ----
    i32x16 hh[2], cr[2];
    #pragma unroll
    for (int r = 0; r < 16; ++r) { hh[0][r] = 0; hh[1][r] = 0; cr[0][r] = 0; cr[1][r] = 0; }
    gemm_i8(s1P, w3h, w3l, m, g, nbase, hh, cr);
    u32 q2p[2][8];
    #pragma unroll
    for (int mt = 0; mt < 2; ++mt) {
      u32 cur = 0;
      #pragma unroll
      for (int r = 0; r < 16; ++r) {
        float v = dr[mt][r] +
            ((float)hh[mt][r] * 65536.0f + (float)cr[mt][r] * 256.0f) * 0x1p-32f;
        u32 e = enc_q(clamp01(v));
        if (r & 1) { q2p[mt][r >> 1] = cur | (e << 16); } else { cur = e; }
      }
    }

    // ---- n1 = clamp(b2 + s0 @ W1^T (bf16) + s2 @ W2^T (i8)) ----
    v16f acc1f[2];
    #pragma unroll
    for (int r = 0; r < 16; ++r) { acc1f[0][r] = b2v; acc1f[1][r] = b2v; }
    {
      s8b bh1 = *(const s8b*)(w1h + (nbase + m) * 16 + g * 8);
      s8b bl1 = *(const s8b*)(w1l + (nbase + m) * 16 + g * 8);
      #pragma unroll
      for (int mt = 0; mt < 2; ++mt) {
        s8b ah = *(const s8b*)(s0h + (32 * mt + m) * 16 + g * 8);
        s8b al = *(const s8b*)(s0l + (32 * mt + m) * 16 + g * 8);
        acc1f[mt] = mfma32(ah, bh1, acc1f[mt]);
        acc1f[mt] = mfma32(al, bh1, acc1f[mt]);
        acc1f[mt] = mfma32(ah, bl1, acc1f[mt]);
      }
    }
    #pragma unroll
    for (int r = 0; r < 16; ++r) { hh[0][r] = 0; hh[1][r] = 0; cr[0][r] = 0; cr[1][r] = 0; }
    gemm_i8(s2P, w2h, w2l, m, g, nbase, hh, cr);
    u32 q1p[2][8];
    #pragma unroll
    for (int mt = 0; mt < 2; ++mt) {
      u32 cur = 0;
      #pragma unroll
      for (int r = 0; r < 16; ++r) {
        float v = acc1f[mt][r] +
            ((float)hh[mt][r] * 65536.0f + (float)cr[mt][r] * 256.0f) * 0x1p-32f;
        u32 e = enc_q(clamp01(v));
        if (r & 1) { q1p[mt][r >> 1] = cur | (e << 16); } else { cur = e; }
      }
    }

    // ---- n0 = clamp(b0 + s1 @ W0^T), 16x16x64 i8, waves 0-3 ----
    float v0[4];
    if (w < 4) {
      i32x4 whh, wcr;
      whh.x = whh.y = whh.z = whh.w = 0;
      wcr.x = wcr.y = wcr.z = wcr.w = 0;
      const int arow = 16 * w + m16;
      const int sxw = arow & 3;
      const u16* ap = s1P + arow * 256;
      #pragma unroll
      for (int kt = 0; kt < 4; ++kt) {
        const int sl = kt * 4 + g4;
        const int so = ((sl ^ sxw) << 4);
        u32x4 A  = *(const u32x4*)(ap + so);
        u32x4 Ab = *(const u32x4*)(ap + so + 8);
        i32x4 ah, al; unpack_hl(A, Ab, ah, al);
        i32x4 bh = *(const i32x4*)(w0h + m16 * 256 + kt * 64 + g4 * 16);
        i32x4 bl = *(const i32x4*)(w0l + m16 * 256 + kt * 64 + g4 * 16);
        whh = mfma_i8_16(ah, bh, whh);
        wcr = mfma_i8_16(al, bh, wcr);
        wcr = mfma_i8_16(ah, bl, wcr);
      }
      #pragma unroll
      for (int r = 0; r < 4; ++r)
        v0[r] = clamp01(b0v + ((float)whh[r] * 65536.0f + (float)wcr[r] * 256.0f) * 0x1p-32f);
    }

    __syncthreads();   // all reads of old state done

    // ---- write back new states ----
    #pragma unroll
    for (int mt = 0; mt < 2; ++mt)
      #pragma unroll
      for (int r = 0; r < 16; ++r) {
        int row = 32 * mt + (r & 3) + 8 * (r >> 2) + 4 * g;
        int idx = row * 256 + (((cslot ^ (row & 3)) << 4)) + cm;
        u16 e1 = (u16)(q1p[mt][r >> 1] >> (16 * (r & 1)));
        u16 e2 = (u16)(q2p[mt][r >> 1] >> (16 * (r & 1)));
        s1P[idx] = e1;
        s2P[idx] = e2;
        if (last) {
          out1[(size_t)(rb + row) * 256 + nbase + m] = dec_q(e1);
          out2[(size_t)(rb + row) * 256 + nbase + m] = dec_q(e2);
        }
      }
    if (w < 4 && m16 < 10) {
      #pragma unroll
      for (int r = 0; r < 4; ++r) {
        int row = 16 * w + g4 * 4 + r;
        u16 h, lo; split1(v0[r], h, lo);
        s0h[row * 16 + m16] = h;
        s0l[row * 16 + m16] = lo;
        if (last) out0[(rb + row) * 10 + m16] = v0[r];
      }
    }
    __syncthreads();   // new state visible
  }
}

// ---------------- launcher ---------------------------------------------------
extern "C" void kernel_launch(void* const* d_in, const int* in_sizes, int n_in,
                              void* d_out, int out_size, void* d_ws, size_t ws_size,
                              hipStream_t stream) {
  const float* data = (const float*)d_in[0];
  const float* s0g  = (const float*)d_in[1];
  const float* s1g  = (const float*)d_in[2];
  const float* s2g  = (const float*)d_in[3];
  const float* W0   = (const float*)d_in[4];
  const float* b0   = (const float*)d_in[5];
  const float* W1   = (const float*)d_in[6];
  const float* W2   = (const float*)d_in[7];
  const float* b2   = (const float*)d_in[8];
  const float* W3   = (const float*)d_in[9];
  const float* W4   = (const float*)d_in[10];
  const float* b4   = (const float*)d_in[11];
  const int*   Tp   = (const int*)d_in[12];

  char* ws = (char*)d_ws;
  float* drive = (float*)ws;                                  // 16 MB
  size_t off = 16777216;
  signed char* w2h = (signed char*)(ws + off); off += 65536;
  signed char* w2l = (signed char*)(ws + off); off += 65536;
  signed char* w3h = (signed char*)(ws + off); off += 65536;
  signed char* w3l = (signed char*)(ws + off); off += 65536;
  signed char* w0h = (signed char*)(ws + off); off += 4096;
  signed char* w0l = (signed char*)(ws + off); off += 4096;
  u16* w4h = (u16*)(ws + off); off += 401408;
  u16* w4l = (u16*)(ws + off); off += 401408;
  u16* w1h = (u16*)(ws + off); off += 8192;
  u16* w1l = (u16*)(ws + off); off += 8192;
  float* b0p = (float*)(ws + off); off += 64;

  float* out0 = (float*)d_out;
  float* out1 = out0 + 16384 * 10;
  float* out2 = out1 + 16384 * 256;

  hipFuncSetAttribute((const void*)k_main,
                      hipFuncAttributeMaxDynamicSharedMemorySize, 69632);

  k_prep_w<<<784, 256, 0, stream>>>(W2, W3, W4, W0, w2h, w2l, w3h, w3l,
                                    w0h, w0l, w4h, w4l);
  k_prep_small<<<17, 256, 0, stream>>>(W1, b0, w1h, w1l, b0p);
  k_drive<<<256, 256, 0, stream>>>(data, w4h, w4l, b4, drive);
  k_main<<<256, 512, 69632, stream>>>(s0g, s1g, s2g, b2, Tp,
      w2h, w2l, w3h, w3l, w0h, w0l, w1h, w1l, b0p, drive, out0, out1, out2);
}

// Round 3
// 1332.443 us; speedup vs baseline: 4.3968x; 1.3303x over previous
//
#include <hip/hip_runtime.h>

typedef __attribute__((ext_vector_type(8))) short s8b;       // 8 x bf16
typedef __attribute__((ext_vector_type(16))) float v16f;     // 32x32 f32 acc
typedef __attribute__((ext_vector_type(4)))  float v4f;
typedef __attribute__((ext_vector_type(4)))  unsigned int u32x4;
typedef __attribute__((ext_vector_type(4)))  int i32x4;      // 16 x i8 operand
typedef __attribute__((ext_vector_type(16))) int i32x16;     // 32x32 i32 acc
typedef unsigned short u16;
typedef unsigned int u32;

__device__ __forceinline__ float clamp01(float v) {
  return __builtin_fminf(__builtin_fmaxf(v, 0.0f), 1.0f);
}

__device__ __forceinline__ void split1(float f, u16 &h, u16 &l) {
  unsigned u = __builtin_bit_cast(unsigned, f);
  unsigned hu = u & 0xffff0000u;
  float lf = f - __builtin_bit_cast(float, hu);
  h = (u16)(u >> 16);
  l = (u16)(__builtin_bit_cast(unsigned, lf) >> 16);
}

__device__ __forceinline__ v16f mfma32(s8b a, s8b b, v16f c) {
  return __builtin_amdgcn_mfma_f32_32x32x16_bf16(a, b, c, 0, 0, 0);
}
__device__ __forceinline__ i32x16 mfma_i8_32(i32x4 a, i32x4 b, i32x16 c) {
  return __builtin_amdgcn_mfma_i32_32x32x32_i8(a, b, c, 0, 0, 0);
}
__device__ __forceinline__ i32x4 mfma_i8_16(i32x4 a, i32x4 b, i32x4 c) {
  return __builtin_amdgcn_mfma_i32_16x16x64_i8(a, b, c, 0, 0, 0);
}

// state Q14: packed u16 = h (0..64, low byte) | l (signed, high byte)
__device__ __forceinline__ u16 enc_q(float v) {
  int q = (int)rintf(v * 16384.0f);
  int h = (q + 128) >> 8;
  int lo = q - (h << 8);
  return (u16)((h & 0xff) | ((lo & 0xff) << 8));
}

// unpack 16 packed u16 -> h-frag / l-frag (i8x16 each) via v_perm
__device__ __forceinline__ void unpack_hl(u32x4 A, u32x4 B, i32x4 &h, i32x4 &l) {
  const unsigned SH = 0x06040200u, SL = 0x07050301u;
  h.x = (int)__builtin_amdgcn_perm(A.y, A.x, SH);
  h.y = (int)__builtin_amdgcn_perm(A.w, A.z, SH);
  h.z = (int)__builtin_amdgcn_perm(B.y, B.x, SH);
  h.w = (int)__builtin_amdgcn_perm(B.w, B.z, SH);
  l.x = (int)__builtin_amdgcn_perm(A.y, A.x, SL);
  l.y = (int)__builtin_amdgcn_perm(A.w, A.z, SL);
  l.z = (int)__builtin_amdgcn_perm(B.y, B.x, SL);
  l.w = (int)__builtin_amdgcn_perm(B.w, B.z, SL);
}

// swizzled u16 index in a [64][256] state tile: 16B chunk c=col>>3 -> c^(row&7)
__device__ __forceinline__ int sw_idx(int row, int col) {
  return row * 256 + ((((col >> 3) ^ (row & 7))) << 3) + (col & 7);
}

// ---------------- prep kernels ----------------------------------------------
__global__ void k_prep_w(const float* __restrict__ W2, const float* __restrict__ W3,
                         const float* __restrict__ W4, const float* __restrict__ W0,
                         signed char* __restrict__ w2h, signed char* __restrict__ w2l,
                         signed char* __restrict__ w3h, signed char* __restrict__ w3l,
                         signed char* __restrict__ w0h, signed char* __restrict__ w0l,
                         u16* __restrict__ w4h, u16* __restrict__ w4l) {
  int i = blockIdx.x * 256 + threadIdx.x;
  if (i < 65536) {
    int q = (int)rintf(W2[i] * 262144.0f);
    int h = (q + 128) >> 8; w2h[i] = (signed char)h; w2l[i] = (signed char)(q - (h << 8));
    q = (int)rintf(W3[i] * 262144.0f);
    h = (q + 128) >> 8; w3h[i] = (signed char)h; w3l[i] = (signed char)(q - (h << 8));
  }
  if (i < 4096) {                           // W0 padded [16][256]
    int n = i >> 8, k = i & 255;
    float v = (n < 10) ? W0[n * 256 + k] : 0.0f;
    int q = (int)rintf(v * 262144.0f);
    int h = (q + 128) >> 8; w0h[i] = (signed char)h; w0l[i] = (signed char)(q - (h << 8));
  }
  if (i < 200704) {
    u16 h, lo;
    split1(W4[i], h, lo); w4h[i] = h; w4l[i] = lo;
  }
}

__global__ void k_prep_small(const float* __restrict__ W1, const float* __restrict__ b0,
                             u16* __restrict__ w1h, u16* __restrict__ w1l,
                             float* __restrict__ b0p) {
  int i = blockIdx.x * 256 + threadIdx.x;
  if (i < 4096) {                    // W1 padded [256][16]
    int n = i >> 4, k = i & 15;
    float v = (k < 10) ? W1[n * 10 + k] : 0.0f;
    u16 h, lo; split1(v, h, lo); w1h[i] = h; w1l[i] = lo;
  } else if (i < 4112) {
    int k = i - 4096;
    b0p[k] = (k < 10) ? b0[k] : 0.0f;
  }
}

// ---------------- drive = data @ W4^T + b4 (bf16 3-pass, once) ---------------
__device__ __forceinline__ void split_pack8(v4f x0, v4f x1, s8b &hi, s8b &lo) {
  float f[8];
  #pragma unroll
  for (int j = 0; j < 4; ++j) { f[j] = x0[j]; f[4 + j] = x1[j]; }
  u32x4 vh, vl;
  #pragma unroll
  for (int j = 0; j < 4; ++j) {
    unsigned u0 = __builtin_bit_cast(unsigned, f[2 * j]);
    unsigned u1 = __builtin_bit_cast(unsigned, f[2 * j + 1]);
    unsigned h0 = u0 & 0xffff0000u, h1 = u1 & 0xffff0000u;
    float l0 = f[2 * j]     - __builtin_bit_cast(float, h0);
    float l1 = f[2 * j + 1] - __builtin_bit_cast(float, h1);
    vh[j] = (u0 >> 16) | h1;
    vl[j] = (__builtin_bit_cast(unsigned, l0) >> 16) |
            (__builtin_bit_cast(unsigned, l1) & 0xffff0000u);
  }
  hi = __builtin_bit_cast(s8b, vh);
  lo = __builtin_bit_cast(s8b, vl);
}

__global__ void __launch_bounds__(256, 1) k_drive(
    const float* __restrict__ data, const u16* __restrict__ w4h,
    const u16* __restrict__ w4l, const float* __restrict__ b4,
    float* __restrict__ drive) {
  const int tid = threadIdx.x;
  const int w = tid >> 6, l = tid & 63;
  const int m = l & 31, g = l >> 5;
  const int rb = blockIdx.x * 64;
  const int nbase = w * 64;
  float b4v0 = b4[nbase + m], b4v1 = b4[nbase + 32 + m];
  v16f acc[2][2];
  #pragma unroll
  for (int r = 0; r < 16; ++r) {
    acc[0][0][r] = b4v0; acc[0][1][r] = b4v1;
    acc[1][0][r] = b4v0; acc[1][1][r] = b4v1;
  }
  for (int kt = 0; kt < 49; ++kt) {
    int k0 = kt * 16 + g * 8;
    s8b aH[2], aL[2], bH[2], bL[2];
    #pragma unroll
    for (int mt = 0; mt < 2; ++mt) {
      const float* p = data + (size_t)(rb + 32 * mt + m) * 784 + k0;
      v4f x0 = *(const v4f*)p;
      v4f x1 = *(const v4f*)(p + 4);
      split_pack8(x0, x1, aH[mt], aL[mt]);
    }
    #pragma unroll
    for (int nt = 0; nt < 2; ++nt) {
      int off = (nbase + 32 * nt + m) * 784 + k0;
      bH[nt] = *(const s8b*)(w4h + off);
      bL[nt] = *(const s8b*)(w4l + off);
    }
    #pragma unroll
    for (int mt = 0; mt < 2; ++mt)
      #pragma unroll
      for (int nt = 0; nt < 2; ++nt) {
        acc[mt][nt] = mfma32(aH[mt], bH[nt], acc[mt][nt]);
        acc[mt][nt] = mfma32(aL[mt], bH[nt], acc[mt][nt]);
        acc[mt][nt] = mfma32(aH[mt], bL[nt], acc[mt][nt]);
      }
  }
  #pragma unroll
  for (int mt = 0; mt < 2; ++mt)
    #pragma unroll
    for (int nt = 0; nt < 2; ++nt)
      #pragma unroll
      for (int r = 0; r < 16; ++r) {
        int row = rb + 32 * mt + (r & 3) + 8 * (r >> 2) + 4 * g;
        int col = nbase + 32 * nt + m;
        drive[(size_t)row * 256 + col] = acc[mt][nt][r];
      }
}

// ---------------- main persistent stepper ------------------------------------
// one m-tile (32 rows) of a K=256 i8 gemm; weights in registers
__device__ __forceinline__ void gemm_tile(const u16* __restrict__ sP, int arow,
    const i32x4* bh, const i32x4* bl, int g,
    i32x16 &hh, i32x16 &c1, i32x16 &c2) {
  const int rsh = (arow & 7) << 3;
  const u16* ap = sP + arow * 256;
  #pragma unroll
  for (int kt = 0; kt < 8; ++kt) {
    const int s = 2 * kt + g;
    const int i0 = (s << 4) ^ rsh;
    u32x4 A0 = *(const u32x4*)(ap + i0);
    u32x4 A1 = *(const u32x4*)(ap + (i0 ^ 8));
    i32x4 ah, al; unpack_hl(A0, A1, ah, al);
    hh = mfma_i8_32(ah, bh[kt], hh);
    c1 = mfma_i8_32(al, bh[kt], c1);
    c2 = mfma_i8_32(ah, bl[kt], c2);
  }
}

__global__ void __launch_bounds__(512, 2) k_main(
    const float* __restrict__ s0g, const float* __restrict__ s1g,
    const float* __restrict__ s2g, const float* __restrict__ b2,
    const int* __restrict__ Tp,
    const signed char* __restrict__ w2h, const signed char* __restrict__ w2l,
    const signed char* __restrict__ w3h, const signed char* __restrict__ w3l,
    const signed char* __restrict__ w0h, const signed char* __restrict__ w0l,
    const u16* __restrict__ w1h, const u16* __restrict__ w1l,
    const float* __restrict__ b0p, const float* __restrict__ drive,
    float* __restrict__ out0, float* __restrict__ out1, float* __restrict__ out2) {
  extern __shared__ u16 smem[];
  u16* s1A = smem;                 // [64][256] u16, swizzled (32 KB each)
  u16* s1B = smem + 16384;
  u16* s2A = smem + 32768;
  u16* s2B = smem + 49152;
  u16* s0hA = smem + 65536;        // [64][16] u16 (2 KB each)
  u16* s0lA = smem + 66560;
  u16* s0hB = smem + 67584;
  u16* s0lB = smem + 68608;
  signed char* w0hs = (signed char*)(smem + 69632);  // [16][256] i8 swizzled
  signed char* w0ls = w0hs + 4096;                   // total 147456 B

  const int tid = threadIdx.x;
  const int w = tid >> 6, l = tid & 63;
  const int m = l & 31, g = l >> 5;
  const int m16 = l & 15, g4 = l >> 4;
  const int rb = blockIdx.x * 64;
  const int nbase = w * 32;
  const int col = nbase + m;

  // ---- stage weights into registers (once) ----
  i32x4 w2hF[8], w2lF[8], w3hF[8], w3lF[8];
  {
    const int wo = col * 256 + g * 16;
    #pragma unroll
    for (int kt = 0; kt < 8; ++kt) {
      w2hF[kt] = *(const i32x4*)(w2h + wo + kt * 32);
      w2lF[kt] = *(const i32x4*)(w2l + wo + kt * 32);
      w3hF[kt] = *(const i32x4*)(w3h + wo + kt * 32);
      w3lF[kt] = *(const i32x4*)(w3l + wo + kt * 32);
    }
  }
  const s8b w1hf = *(const s8b*)(w1h + col * 16 + g * 8);
  const s8b w1lf = *(const s8b*)(w1l + col * 16 + g * 8);

  // ---- init LDS states ----
  for (int i = tid; i < 16384; i += 512) {
    int row = i >> 8, c = i & 255;
    int idx = sw_idx(row, c);
    s1A[idx] = enc_q(s1g[(size_t)(rb + row) * 256 + c]);
    s2A[idx] = enc_q(s2g[(size_t)(rb + row) * 256 + c]);
  }
  for (int i = tid; i < 1024; i += 512) {
    int row = i >> 4, c = i & 15;
    float v = (c < 10) ? s0g[(rb + row) * 10 + c] : 0.0f;
    u16 h, lo; split1(v, h, lo);
    s0hA[i] = h; s0lA[i] = lo;
    s0hB[i] = 0; s0lB[i] = 0;       // pre-zero other buffer (padding cols stay 0)
  }
  if (tid < 256) {                  // stage W0 into LDS, swizzled
    int r = tid >> 4, c = tid & 15;
    int dst = r * 256 + ((c ^ (r & 7)) << 4);
    *(u32x4*)(w0hs + dst) = *(const u32x4*)(w0h + r * 256 + c * 16);
    *(u32x4*)(w0ls + dst) = *(const u32x4*)(w0l + r * 256 + c * 16);
  }

  const float b2v = b2[col];
  const float b0v = b0p[m16];
  float dr[2][16];
  #pragma unroll
  for (int mt = 0; mt < 2; ++mt)
    #pragma unroll
    for (int r = 0; r < 16; ++r) {
      int row = rb + 32 * mt + (r & 3) + 8 * (r >> 2) + 4 * g;
      dr[mt][r] = drive[(size_t)row * 256 + col];
    }
  const int T = Tp[0];
  const int cq = col >> 3, cw = col & 7;   // write-back chunk/offset
  __syncthreads();

  u16 *s1c = s1A, *s1n = s1B, *s2c = s2A, *s2n = s2B;
  u16 *s0hc = s0hA, *s0lc = s0lA, *s0hn = s0hB, *s0ln = s0lB;

  for (int t = 0; t < T; ++t) {
    const bool last = (t == T - 1);

    // ---- n2 = clamp(drive + s1 @ W3^T) ----
    #pragma unroll
    for (int mt = 0; mt < 2; ++mt) {
      i32x16 hh, c1, c2;
      #pragma unroll
      for (int r = 0; r < 16; ++r) { hh[r] = 0; c1[r] = 0; c2[r] = 0; }
      gemm_tile(s1c, 32 * mt + m, w3hF, w3lF, g, hh, c1, c2);
      #pragma unroll
      for (int r = 0; r < 16; ++r) {
        float v = clamp01(dr[mt][r] +
            ((float)hh[r] * 65536.0f + (float)(c1[r] + c2[r]) * 256.0f) * 0x1p-32f);
        int row = 32 * mt + (r & 3) + 8 * (r >> 2) + 4 * g;
        s2n[row * 256 + ((cq ^ (row & 7)) << 3) + cw] = enc_q(v);
        if (last) out2[(size_t)(rb + row) * 256 + col] = v;
      }
    }

    // ---- n1 = clamp(b2 + s2 @ W2^T + s0 @ W1^T) ----
    #pragma unroll
    for (int mt = 0; mt < 2; ++mt) {
      i32x16 hh, c1, c2;
      #pragma unroll
      for (int r = 0; r < 16; ++r) { hh[r] = 0; c1[r] = 0; c2[r] = 0; }
      gemm_tile(s2c, 32 * mt + m, w2hF, w2lF, g, hh, c1, c2);
      v16f af;
      #pragma unroll
      for (int r = 0; r < 16; ++r)
        af[r] = b2v + ((float)hh[r] * 65536.0f + (float)(c1[r] + c2[r]) * 256.0f) * 0x1p-32f;
      s8b ah = *(const s8b*)(s0hc + (32 * mt + m) * 16 + g * 8);
      s8b al = *(const s8b*)(s0lc + (32 * mt + m) * 16 + g * 8);
      af = mfma32(ah, w1hf, af);
      af = mfma32(al, w1hf, af);
      af = mfma32(ah, w1lf, af);
      #pragma unroll
      for (int r = 0; r < 16; ++r) {
        float v = clamp01(af[r]);
        int row = 32 * mt + (r & 3) + 8 * (r >> 2) + 4 * g;
        s1n[row * 256 + ((cq ^ (row & 7)) << 3) + cw] = enc_q(v);
        if (last) out1[(size_t)(rb + row) * 256 + col] = v;
      }
    }

    // ---- n0 = clamp(b0 + s1 @ W0^T), waves 0-3, 16x16x64 ----
    if (w < 4) {
      const int arow = 16 * w + m16;
      const int rsh = (arow & 7) << 3;
      const u16* ap = s1c + arow * 256;
      i32x4 ph, p1, p2;
      ph.x = ph.y = ph.z = ph.w = 0;
      p1.x = p1.y = p1.z = p1.w = 0;
      p2.x = p2.y = p2.z = p2.w = 0;
      #pragma unroll
      for (int kt = 0; kt < 4; ++kt) {
        const int s = kt * 4 + g4;
        const int i0 = (s << 4) ^ rsh;
        u32x4 A0 = *(const u32x4*)(ap + i0);
        u32x4 A1 = *(const u32x4*)(ap + (i0 ^ 8));
        i32x4 ah, al; unpack_hl(A0, A1, ah, al);
        const int wc = s ^ (m16 & 7);
        i32x4 bh = *(const i32x4*)(w0hs + m16 * 256 + (wc << 4));
        i32x4 bl = *(const i32x4*)(w0ls + m16 * 256 + (wc << 4));
        ph = mfma_i8_16(ah, bh, ph);
        p1 = mfma_i8_16(al, bh, p1);
        p2 = mfma_i8_16(ah, bl, p2);
      }
      #pragma unroll
      for (int r = 0; r < 4; ++r) {
        float v = clamp01(b0v +
            ((float)ph[r] * 65536.0f + (float)(p1[r] + p2[r]) * 256.0f) * 0x1p-32f);
        int row = 16 * w + g4 * 4 + r;
        if (m16 < 10) {
          u16 h, lo; split1(v, h, lo);
          s0hn[row * 16 + m16] = h;
          s0ln[row * 16 + m16] = lo;
          if (last) out0[(rb + row) * 10 + m16] = v;
        }
      }
    }

    __syncthreads();   // next-state buffers fully written; old fully read
    u16* tp;
    tp = s1c; s1c = s1n; s1n = tp;
    tp = s2c; s2c = s2n; s2n = tp;
    tp = s0hc; s0hc = s0hn; s0hn = tp;
    tp = s0lc; s0lc = s0ln; s0ln = tp;
  }
}

// ---------------- launcher ---------------------------------------------------
extern "C" void kernel_launch(void* const* d_in, const int* in_sizes, int n_in,
                              void* d_out, int out_size, void* d_ws, size_t ws_size,
                              hipStream_t stream) {
  const float* data = (const float*)d_in[0];
  const float* s0g  = (const float*)d_in[1];
  const float* s1g  = (const float*)d_in[2];
  const float* s2g  = (const float*)d_in[3];
  const float* W0   = (const float*)d_in[4];
  const float* b0   = (const float*)d_in[5];
  const float* W1   = (const float*)d_in[6];
  const float* W2   = (const float*)d_in[7];
  const float* b2   = (const float*)d_in[8];
  const float* W3   = (const float*)d_in[9];
  const float* W4   = (const float*)d_in[10];
  const float* b4   = (const float*)d_in[11];
  const int*   Tp   = (const int*)d_in[12];

  char* ws = (char*)d_ws;
  float* drive = (float*)ws;                                  // 16 MB
  size_t off = 16777216;
  signed char* w2h = (signed char*)(ws + off); off += 65536;
  signed char* w2l = (signed char*)(ws + off); off += 65536;
  signed char* w3h = (signed char*)(ws + off); off += 65536;
  signed char* w3l = (signed char*)(ws + off); off += 65536;
  signed char* w0h = (signed char*)(ws + off); off += 4096;
  signed char* w0l = (signed char*)(ws + off); off += 4096;
  u16* w4h = (u16*)(ws + off); off += 401408;
  u16* w4l = (u16*)(ws + off); off += 401408;
  u16* w1h = (u16*)(ws + off); off += 8192;
  u16* w1l = (u16*)(ws + off); off += 8192;
  float* b0p = (float*)(ws + off); off += 64;

  float* out0 = (float*)d_out;
  float* out1 = out0 + 16384 * 10;
  float* out2 = out1 + 16384 * 256;

  hipFuncSetAttribute((const void*)k_main,
                      hipFuncAttributeMaxDynamicSharedMemorySize, 147456);

  k_prep_w<<<784, 256, 0, stream>>>(W2, W3, W4, W0, w2h, w2l, w3h, w3l,
                                    w0h, w0l, w4h, w4l);
  k_prep_small<<<17, 256, 0, stream>>>(W1, b0, w1h, w1l, b0p);
  k_drive<<<256, 256, 0, stream>>>(data, w4h, w4l, b4, drive);
  k_main<<<256, 512, 147456, stream>>>(s0g, s1g, s2g, b2, Tp,
      w2h, w2l, w3h, w3l, w0h, w0l, w1h, w1l, b0p, drive, out0, out1, out2);
}

// Round 4
// 566.457 us; speedup vs baseline: 10.3424x; 2.3522x over previous
//
#include <hip/hip_runtime.h>

typedef __attribute__((ext_vector_type(8))) short s8b;       // 8 x bf16
typedef __attribute__((ext_vector_type(16))) float v16f;     // 32x32 f32 acc
typedef __attribute__((ext_vector_type(4)))  float v4f;
typedef __attribute__((ext_vector_type(4)))  unsigned int u32x4;
typedef __attribute__((ext_vector_type(4)))  int i32x4;      // 16 x i8 operand
typedef __attribute__((ext_vector_type(16))) int i32x16;     // 32x32 i32 acc
typedef unsigned short u16;
typedef unsigned int u32;

__device__ __forceinline__ float clamp01(float v) {
  return __builtin_fminf(__builtin_fmaxf(v, 0.0f), 1.0f);
}

__device__ __forceinline__ void split1(float f, u16 &h, u16 &l) {
  unsigned u = __builtin_bit_cast(unsigned, f);
  unsigned hu = u & 0xffff0000u;
  float lf = f - __builtin_bit_cast(float, hu);
  h = (u16)(u >> 16);
  l = (u16)(__builtin_bit_cast(unsigned, lf) >> 16);
}

__device__ __forceinline__ v16f mfma32(s8b a, s8b b, v16f c) {
  return __builtin_amdgcn_mfma_f32_32x32x16_bf16(a, b, c, 0, 0, 0);
}
__device__ __forceinline__ i32x16 mfma_i8_32(i32x4 a, i32x4 b, i32x16 c) {
  return __builtin_amdgcn_mfma_i32_32x32x32_i8(a, b, c, 0, 0, 0);
}
__device__ __forceinline__ i32x4 mfma_i8_16(i32x4 a, i32x4 b, i32x4 c) {
  return __builtin_amdgcn_mfma_i32_16x16x64_i8(a, b, c, 0, 0, 0);
}

// state Q14: packed u16 = h (0..64, low byte) | l (signed, high byte)
__device__ __forceinline__ u16 enc_q(float v) {
  int q = (int)rintf(v * 16384.0f);
  int h = (q + 128) >> 8;
  int lo = q - (h << 8);
  return (u16)((h & 0xff) | ((lo & 0xff) << 8));
}

// unpack 16 packed u16 -> h-frag / l-frag (i8x16 each) via v_perm
__device__ __forceinline__ void unpack_hl(u32x4 A, u32x4 B, i32x4 &h, i32x4 &l) {
  const unsigned SH = 0x06040200u, SL = 0x07050301u;
  h.x = (int)__builtin_amdgcn_perm(A.y, A.x, SH);
  h.y = (int)__builtin_amdgcn_perm(A.w, A.z, SH);
  h.z = (int)__builtin_amdgcn_perm(B.y, B.x, SH);
  h.w = (int)__builtin_amdgcn_perm(B.w, B.z, SH);
  l.x = (int)__builtin_amdgcn_perm(A.y, A.x, SL);
  l.y = (int)__builtin_amdgcn_perm(A.w, A.z, SL);
  l.z = (int)__builtin_amdgcn_perm(B.y, B.x, SL);
  l.w = (int)__builtin_amdgcn_perm(B.w, B.z, SL);
}

// swizzled u16 index in a [64][256] state tile: 16B chunk c=col>>3 -> c^(row&7)
__device__ __forceinline__ int sw_idx(int row, int col) {
  return row * 256 + ((((col >> 3) ^ (row & 7))) << 3) + (col & 7);
}

// ---------------- prep kernels ----------------------------------------------
// W2/W3/W0 -> single i8 Q11 (|W| <= 1/16 so Q11 fits i8); W4 -> bf16 h/l
__global__ void k_prep_w(const float* __restrict__ W2, const float* __restrict__ W3,
                         const float* __restrict__ W4, const float* __restrict__ W0,
                         signed char* __restrict__ w2q, signed char* __restrict__ w3q,
                         signed char* __restrict__ w0q,
                         u16* __restrict__ w4h, u16* __restrict__ w4l) {
  int i = blockIdx.x * 256 + threadIdx.x;
  if (i < 65536) {
    int q = (int)rintf(W2[i] * 2048.0f);
    q = min(max(q, -127), 127); w2q[i] = (signed char)q;
    q = (int)rintf(W3[i] * 2048.0f);
    q = min(max(q, -127), 127); w3q[i] = (signed char)q;
  }
  if (i < 4096) {                           // W0 padded [16][256]
    int n = i >> 8, k = i & 255;
    float v = (n < 10) ? W0[n * 256 + k] : 0.0f;
    int q = (int)rintf(v * 2048.0f);
    q = min(max(q, -127), 127); w0q[i] = (signed char)q;
  }
  if (i < 200704) {
    u16 h, lo;
    split1(W4[i], h, lo); w4h[i] = h; w4l[i] = lo;
  }
}

__global__ void k_prep_small(const float* __restrict__ W1, const float* __restrict__ b0,
                             u16* __restrict__ w1h, u16* __restrict__ w1l,
                             float* __restrict__ b0p) {
  int i = blockIdx.x * 256 + threadIdx.x;
  if (i < 4096) {                    // W1 padded [256][16]
    int n = i >> 4, k = i & 15;
    float v = (k < 10) ? W1[n * 10 + k] : 0.0f;
    u16 h, lo; split1(v, h, lo); w1h[i] = h; w1l[i] = lo;
  } else if (i < 4112) {
    int k = i - 4096;
    b0p[k] = (k < 10) ? b0[k] : 0.0f;
  }
}

// ---------------- drive = data @ W4^T + b4 (bf16 3-pass, once) ---------------
__device__ __forceinline__ void split_pack8(v4f x0, v4f x1, s8b &hi, s8b &lo) {
  float f[8];
  #pragma unroll
  for (int j = 0; j < 4; ++j) { f[j] = x0[j]; f[4 + j] = x1[j]; }
  u32x4 vh, vl;
  #pragma unroll
  for (int j = 0; j < 4; ++j) {
    unsigned u0 = __builtin_bit_cast(unsigned, f[2 * j]);
    unsigned u1 = __builtin_bit_cast(unsigned, f[2 * j + 1]);
    unsigned h0 = u0 & 0xffff0000u, h1 = u1 & 0xffff0000u;
    float l0 = f[2 * j]     - __builtin_bit_cast(float, h0);
    float l1 = f[2 * j + 1] - __builtin_bit_cast(float, h1);
    vh[j] = (u0 >> 16) | h1;
    vl[j] = (__builtin_bit_cast(unsigned, l0) >> 16) |
            (__builtin_bit_cast(unsigned, l1) & 0xffff0000u);
  }
  hi = __builtin_bit_cast(s8b, vh);
  lo = __builtin_bit_cast(s8b, vl);
}

__global__ void __launch_bounds__(256, 1) k_drive(
    const float* __restrict__ data, const u16* __restrict__ w4h,
    const u16* __restrict__ w4l, const float* __restrict__ b4,
    float* __restrict__ drive) {
  const int tid = threadIdx.x;
  const int w = tid >> 6, l = tid & 63;
  const int m = l & 31, g = l >> 5;
  const int rb = blockIdx.x * 64;
  const int nbase = w * 64;
  float b4v0 = b4[nbase + m], b4v1 = b4[nbase + 32 + m];
  v16f acc[2][2];
  #pragma unroll
  for (int r = 0; r < 16; ++r) {
    acc[0][0][r] = b4v0; acc[0][1][r] = b4v1;
    acc[1][0][r] = b4v0; acc[1][1][r] = b4v1;
  }
  for (int kt = 0; kt < 49; ++kt) {
    int k0 = kt * 16 + g * 8;
    s8b aH[2], aL[2], bH[2], bL[2];
    #pragma unroll
    for (int mt = 0; mt < 2; ++mt) {
      const float* p = data + (size_t)(rb + 32 * mt + m) * 784 + k0;
      v4f x0 = *(const v4f*)p;
      v4f x1 = *(const v4f*)(p + 4);
      split_pack8(x0, x1, aH[mt], aL[mt]);
    }
    #pragma unroll
    for (int nt = 0; nt < 2; ++nt) {
      int off = (nbase + 32 * nt + m) * 784 + k0;
      bH[nt] = *(const s8b*)(w4h + off);
      bL[nt] = *(const s8b*)(w4l + off);
    }
    #pragma unroll
    for (int mt = 0; mt < 2; ++mt)
      #pragma unroll
      for (int nt = 0; nt < 2; ++nt) {
        acc[mt][nt] = mfma32(aH[mt], bH[nt], acc[mt][nt]);
        acc[mt][nt] = mfma32(aL[mt], bH[nt], acc[mt][nt]);
        acc[mt][nt] = mfma32(aH[mt], bL[nt], acc[mt][nt]);
      }
  }
  #pragma unroll
  for (int mt = 0; mt < 2; ++mt)
    #pragma unroll
    for (int nt = 0; nt < 2; ++nt)
      #pragma unroll
      for (int r = 0; r < 16; ++r) {
        int row = rb + 32 * mt + (r & 3) + 8 * (r >> 2) + 4 * g;
        int col = nbase + 32 * nt + m;
        drive[(size_t)row * 256 + col] = acc[mt][nt][r];
      }
}

// ---------------- main persistent stepper ------------------------------------
// both 32-row m-tiles of a K=256 i8 gemm, fused; weights in registers
__device__ __forceinline__ void gemm2(const u16* __restrict__ sP, int m, int g,
    const i32x4* bq, i32x16 &hh0, i32x16 &c10, i32x16 &hh1, i32x16 &c11) {
  const int rs = (m & 7) << 3;          // (m+32)&7 == m&7
  const u16* ap0 = sP + m * 256;
  const u16* ap1 = sP + (m + 32) * 256;
  #pragma unroll
  for (int kt = 0; kt < 8; ++kt) {
    const int s = 2 * kt + g;
    const int i0 = (s << 4) ^ rs;
    u32x4 A0  = *(const u32x4*)(ap0 + i0);
    u32x4 A0b = *(const u32x4*)(ap0 + (i0 ^ 8));
    u32x4 A1  = *(const u32x4*)(ap1 + i0);
    u32x4 A1b = *(const u32x4*)(ap1 + (i0 ^ 8));
    i32x4 a0h, a0l, a1h, a1l;
    unpack_hl(A0, A0b, a0h, a0l);
    unpack_hl(A1, A1b, a1h, a1l);
    hh0 = mfma_i8_32(a0h, bq[kt], hh0);
    c10 = mfma_i8_32(a0l, bq[kt], c10);
    hh1 = mfma_i8_32(a1h, bq[kt], hh1);
    c11 = mfma_i8_32(a1l, bq[kt], c11);
  }
}

__global__ void __launch_bounds__(512, 2) k_main(
    const float* __restrict__ s0g, const float* __restrict__ s1g,
    const float* __restrict__ s2g, const float* __restrict__ b2,
    const int* __restrict__ Tp,
    const signed char* __restrict__ w2q, const signed char* __restrict__ w3q,
    const signed char* __restrict__ w0q,
    const u16* __restrict__ w1h, const u16* __restrict__ w1l,
    const float* __restrict__ b0p, const float* __restrict__ drive,
    float* __restrict__ out0, float* __restrict__ out1, float* __restrict__ out2) {
  extern __shared__ u16 smem[];
  u16* s1A = smem;                 // [64][256] u16, swizzled (32 KB each)
  u16* s1B = smem + 16384;
  u16* s2A = smem + 32768;
  u16* s2B = smem + 49152;
  u16* s0hA = smem + 65536;        // [64][16] u16 (2 KB each)
  u16* s0lA = smem + 66560;
  u16* s0hB = smem + 67584;
  u16* s0lB = smem + 68608;
  signed char* w0s = (signed char*)(smem + 69632);  // [16][256] i8 swizzled, 4 KB

  const int tid = threadIdx.x;
  const int w = tid >> 6, l = tid & 63;
  const int m = l & 31, g = l >> 5;
  const int m16 = l & 15, g4 = l >> 4;
  const int rb = blockIdx.x * 64;
  const int nbase = w * 32;
  const int col = nbase + m;

  // ---- stage weights into registers (once): 32 VGPR each ----
  i32x4 w2F[8], w3F[8];
  {
    const int wo = col * 256 + g * 16;
    #pragma unroll
    for (int kt = 0; kt < 8; ++kt) {
      w2F[kt] = *(const i32x4*)(w2q + wo + kt * 32);
      w3F[kt] = *(const i32x4*)(w3q + wo + kt * 32);
    }
  }
  const s8b w1hf = *(const s8b*)(w1h + col * 16 + g * 8);
  const s8b w1lf = *(const s8b*)(w1l + col * 16 + g * 8);

  // ---- init LDS states ----
  for (int i = tid; i < 16384; i += 512) {
    int row = i >> 8, c = i & 255;
    int idx = sw_idx(row, c);
    s1A[idx] = enc_q(s1g[(size_t)(rb + row) * 256 + c]);
    s2A[idx] = enc_q(s2g[(size_t)(rb + row) * 256 + c]);
  }
  for (int i = tid; i < 1024; i += 512) {
    int row = i >> 4, c = i & 15;
    float v = (c < 10) ? s0g[(rb + row) * 10 + c] : 0.0f;
    u16 h, lo; split1(v, h, lo);
    s0hA[i] = h; s0lA[i] = lo;
    s0hB[i] = 0; s0lB[i] = 0;
  }
  if (tid < 256) {                  // stage W0 into LDS, swizzled (16B chunks)
    int r = tid >> 4, c = tid & 15;
    int dst = r * 256 + ((c ^ (r & 7)) << 4);
    *(u32x4*)(w0s + dst) = *(const u32x4*)(w0q + r * 256 + c * 16);
  }

  const float b2v = b2[col];
  const float b0v = b0p[m16];
  float dr[2][16];
  #pragma unroll
  for (int mt = 0; mt < 2; ++mt)
    #pragma unroll
    for (int r = 0; r < 16; ++r) {
      int row = rb + 32 * mt + (r & 3) + 8 * (r >> 2) + 4 * g;
      dr[mt][r] = drive[(size_t)row * 256 + col];
    }
  const int T = Tp[0];
  const int cq = col >> 3, cw = col & 7;   // write-back chunk/offset
  __syncthreads();

  u16 *s1c = s1A, *s1n = s1B, *s2c = s2A, *s2n = s2B;
  u16 *s0hc = s0hA, *s0lc = s0lA, *s0hn = s0hB, *s0ln = s0lB;

  for (int t = 0; t < T; ++t) {
    const bool last = (t == T - 1);
    i32x16 hh0, c10, hh1, c11;

    // ---- n2 = clamp(drive + s1 @ W3^T) ----
    #pragma unroll
    for (int r = 0; r < 16; ++r) { hh0[r] = 0; c10[r] = 0; hh1[r] = 0; c11[r] = 0; }
    gemm2(s1c, m, g, w3F, hh0, c10, hh1, c11);
    #pragma unroll
    for (int mt = 0; mt < 2; ++mt) {
      #pragma unroll
      for (int r = 0; r < 16; ++r) {
        int iv = mt ? ((hh1[r] << 8) + c11[r]) : ((hh0[r] << 8) + c10[r]);
        float v = clamp01(dr[mt][r] + (float)iv * 0x1p-25f);
        int row = 32 * mt + (r & 3) + 8 * (r >> 2) + 4 * g;
        s2n[row * 256 + ((cq ^ (row & 7)) << 3) + cw] = enc_q(v);
        if (last) out2[(size_t)(rb + row) * 256 + col] = v;
      }
    }

    // ---- n1 = clamp(b2 + s2 @ W2^T + s0 @ W1^T) ----
    #pragma unroll
    for (int r = 0; r < 16; ++r) { hh0[r] = 0; c10[r] = 0; hh1[r] = 0; c11[r] = 0; }
    gemm2(s2c, m, g, w2F, hh0, c10, hh1, c11);
    #pragma unroll
    for (int mt = 0; mt < 2; ++mt) {
      v16f af;
      #pragma unroll
      for (int r = 0; r < 16; ++r) {
        int iv = mt ? ((hh1[r] << 8) + c11[r]) : ((hh0[r] << 8) + c10[r]);
        af[r] = b2v + (float)iv * 0x1p-25f;
      }
      s8b ah = *(const s8b*)(s0hc + (32 * mt + m) * 16 + g * 8);
      s8b al = *(const s8b*)(s0lc + (32 * mt + m) * 16 + g * 8);
      af = mfma32(ah, w1hf, af);
      af = mfma32(al, w1hf, af);
      af = mfma32(ah, w1lf, af);
      #pragma unroll
      for (int r = 0; r < 16; ++r) {
        float v = clamp01(af[r]);
        int row = 32 * mt + (r & 3) + 8 * (r >> 2) + 4 * g;
        s1n[row * 256 + ((cq ^ (row & 7)) << 3) + cw] = enc_q(v);
        if (last) out1[(size_t)(rb + row) * 256 + col] = v;
      }
    }

    // ---- n0 = clamp(b0 + s1 @ W0^T), waves 0-3, 16x16x64 ----
    if (w < 4) {
      const int arow = 16 * w + m16;
      const int rsh = (arow & 7) << 3;
      const u16* ap = s1c + arow * 256;
      i32x4 ph, p1;
      ph.x = ph.y = ph.z = ph.w = 0;
      p1.x = p1.y = p1.z = p1.w = 0;
      #pragma unroll
      for (int kt = 0; kt < 4; ++kt) {
        const int s = kt * 4 + g4;
        const int i0 = (s << 4) ^ rsh;
        u32x4 A0 = *(const u32x4*)(ap + i0);
        u32x4 A1 = *(const u32x4*)(ap + (i0 ^ 8));
        i32x4 ah, al; unpack_hl(A0, A1, ah, al);
        const int wc = s ^ (m16 & 7);
        i32x4 bq = *(const i32x4*)(w0s + m16 * 256 + (wc << 4));
        ph = mfma_i8_16(ah, bq, ph);
        p1 = mfma_i8_16(al, bq, p1);
      }
      #pragma unroll
      for (int r = 0; r < 4; ++r) {
        float v = clamp01(b0v + (float)((ph[r] << 8) + p1[r]) * 0x1p-25f);
        int row = 16 * w + g4 * 4 + r;
        if (m16 < 10) {
          u16 h, lo; split1(v, h, lo);
          s0hn[row * 16 + m16] = h;
          s0ln[row * 16 + m16] = lo;
          if (last) out0[(rb + row) * 10 + m16] = v;
        }
      }
    }

    __syncthreads();   // next-state buffers fully written; old fully read
    u16* tp;
    tp = s1c; s1c = s1n; s1n = tp;
    tp = s2c; s2c = s2n; s2n = tp;
    tp = s0hc; s0hc = s0hn; s0hn = tp;
    tp = s0lc; s0lc = s0ln; s0ln = tp;
  }
}

// ---------------- launcher ---------------------------------------------------
extern "C" void kernel_launch(void* const* d_in, const int* in_sizes, int n_in,
                              void* d_out, int out_size, void* d_ws, size_t ws_size,
                              hipStream_t stream) {
  const float* data = (const float*)d_in[0];
  const float* s0g  = (const float*)d_in[1];
  const float* s1g  = (const float*)d_in[2];
  const float* s2g  = (const float*)d_in[3];
  const float* W0   = (const float*)d_in[4];
  const float* b0   = (const float*)d_in[5];
  const float* W1   = (const float*)d_in[6];
  const float* W2   = (const float*)d_in[7];
  const float* b2   = (const float*)d_in[8];
  const float* W3   = (const float*)d_in[9];
  const float* W4   = (const float*)d_in[10];
  const float* b4   = (const float*)d_in[11];
  const int*   Tp   = (const int*)d_in[12];

  char* ws = (char*)d_ws;
  float* drive = (float*)ws;                                  // 16 MB
  size_t off = 16777216;
  signed char* w2q = (signed char*)(ws + off); off += 65536;
  signed char* w3q = (signed char*)(ws + off); off += 65536;
  signed char* w0q = (signed char*)(ws + off); off += 4096;
  u16* w4h = (u16*)(ws + off); off += 401408;
  u16* w4l = (u16*)(ws + off); off += 401408;
  u16* w1h = (u16*)(ws + off); off += 8192;
  u16* w1l = (u16*)(ws + off); off += 8192;
  float* b0p = (float*)(ws + off); off += 64;

  float* out0 = (float*)d_out;
  float* out1 = out0 + 16384 * 10;
  float* out2 = out1 + 16384 * 256;

  hipFuncSetAttribute((const void*)k_main,
                      hipFuncAttributeMaxDynamicSharedMemorySize, 143360);

  k_prep_w<<<784, 256, 0, stream>>>(W2, W3, W4, W0, w2q, w3q, w0q, w4h, w4l);
  k_prep_small<<<17, 256, 0, stream>>>(W1, b0, w1h, w1l, b0p);
  k_drive<<<256, 256, 0, stream>>>(data, w4h, w4l, b4, drive);
  k_main<<<256, 512, 143360, stream>>>(s0g, s1g, s2g, b2, Tp,
      w2q, w3q, w0q, w1h, w1l, b0p, drive, out0, out1, out2);
}